// Round 9
// baseline (244.561 us; speedup 1.0000x reference)
//
#include <hip/hip_runtime.h>
#include <cstdint>
#include <cstddef>

// ---------------------------------------------------------------------------
// Attention_84155589198714: qkv = ctx @ W + b; causal softmax(q k^T / sqrt(N)); @ v
// B=4, N=2048, D=1024. All GEMMs in bf16 MFMA (16x16x32), fp32 accumulate.
//
// R2: XOR bank swizzle (conflicts -> 0); gld16 mainloop = 700 TF at 6 blk/CU.
// R4/R14/R15: fusion/merge lessons: only merge within one VGPR class;
//   boundary savings ~= occupancy losses otherwise.
// R9-R12: 256-wide tiles + counted-vmcnt schedules: neutral/worse. ABANDONED.
// R16: XCD-chunked swizzle on gemm: FETCH 136->57MB, 80.5->77.2us, MfmaUtil
//   27.9%.  Falsifier fired: gemm is issue-stall-bound at its structural
//   floor (~77us).  GEMM frozen.
// R17 (this): scores+pv (81us @ ~448 TF) run 16 MFMA/barrier vs the gemm's
//   32 with the same staging+sync cost -- exactly the 641/448 ratio.  The
//   old "128x128 scores = 2 blk/CU" note contradicts register arithmetic
//   (scores-128x128 IS mma_mainloop: 32KB LDS, acc[4][4], lean epilogue =
//   gemm's class).  Convert BOTH to 128x128 on the proven mainloop:
//   scores: triangular (qb,kb<=qb) 136 tiles/batch, 544 blocks, K=16.
//   pv: 512 blocks longest-first, K=(qb+1)*2.  Separate dispatches =
//   per-kernel counter attribution.  Falsifier: VGPR>=128 or occ halved ->
//   revert that kernel.
// ---------------------------------------------------------------------------

typedef __attribute__((ext_vector_type(8))) __bf16 bf16x8;
typedef __attribute__((ext_vector_type(4))) float f32x4;

__device__ inline unsigned short f2bf(float f) {
  unsigned u = __float_as_uint(f);
  u = (u + 0x7FFFu + ((u >> 16) & 1u)) >> 16;  // RNE
  return (unsigned short)u;
}

__device__ inline void gld16(const void* g, void* l) {
  __builtin_amdgcn_global_load_lds(
      (const __attribute__((address_space(1))) unsigned int*)g,
      (__attribute__((address_space(3))) unsigned int*)l, 16, 0, 0);
}

// --------------------- 128x128 tile machinery (all GEMMs) ------------------
// LDS layout per tile: row r = 64 elems at r*64; 8-elem chunk c of row r at
// chunk position c ^ (r&7) (XOR bank swizzle). Swapped-operand MFMA:
// output lane&15 = m (A row), 4 acc regs = 4 consecutive n (B row).
__device__ inline void compute_tiles(const unsigned short* As, const unsigned short* Bs,
                                     int lane, int ry, int rx, f32x4 acc[4][4]) {
#pragma unroll
  for (int kk = 0; kk < 64; kk += 32) {
    const int cbase = (kk >> 3) + (lane >> 4);
    const int csw = ((cbase ^ (lane & 7)) << 3);
    bf16x8 a[4], b[4];
#pragma unroll
    for (int mi = 0; mi < 4; mi++)
      a[mi] = *(const bf16x8*)&As[(ry + mi * 16 + (lane & 15)) * 64 + csw];
#pragma unroll
    for (int nj = 0; nj < 4; nj++)
      b[nj] = *(const bf16x8*)&Bs[(rx + nj * 16 + (lane & 15)) * 64 + csw];
#pragma unroll
    for (int mi = 0; mi < 4; mi++)
#pragma unroll
      for (int nj = 0; nj < 4; nj++)
        acc[mi][nj] = __builtin_amdgcn_mfma_f32_16x16x32_bf16(b[nj], a[mi], acc[mi][nj], 0, 0, 0);
  }
}

__device__ inline void mma_mainloop(unsigned short* As, unsigned short* Bs,
                                    const unsigned short* Abase, long strideA,
                                    const unsigned short* Bbase, long strideB,
                                    int kIters, f32x4 acc[4][4]) {
  const int lane = threadIdx.x & 63, wave = threadIdx.x >> 6;
  const int ry = (wave >> 1) * 64, rx = (wave & 1) * 64;
  const int lrow = lane >> 3;
  const int lcol = ((lane & 7) ^ lrow) * 8;
#pragma unroll
  for (int mi = 0; mi < 4; mi++)
#pragma unroll
    for (int nj = 0; nj < 4; nj++) acc[mi][nj] = (f32x4)(0.f);
  for (int kt = 0; kt < kIters; kt++) {
    const int k0 = kt * 64;
    __syncthreads();
#pragma unroll
    for (int c = 0; c < 4; c++) {
      const int q = wave * 4 + c;
      const int row = q * 8 + lrow;
      gld16(Abase + (size_t)row * strideA + k0 + lcol, &As[q * 512]);
      gld16(Bbase + (size_t)row * strideB + k0 + lcol, &Bs[q * 512]);
    }
    __syncthreads();
    compute_tiles(As, Bs, lane, ry, rx, acc);
  }
}

// ------------------------ prep kernel (merged) -----------------------------
// bid < 2048: bf16 convert of ctx, 4 float4/thread (2048*1024 float4 total).
// 2048 <= bid < 2816: W [1024][3072] -> Wt [3072][1024] bf16 (768 64x64 tiles).
// bid == 2816: zero lsum (8192 floats).
__global__ void k_prep(const float* __restrict__ x, unsigned short* __restrict__ y,
                       const float* __restrict__ W, unsigned short* __restrict__ Wt,
                       float* __restrict__ lsum) {
  __shared__ unsigned short sm[64 * 65];
  const int bid = blockIdx.x;
  if (bid < 2048) {
#pragma unroll
    for (int k = 0; k < 4; k++) {
      const int i = bid * 1024 + k * 256 + threadIdx.x;
      float4 v = ((const float4*)x)[i];
      ushort4 o;
      o.x = f2bf(v.x); o.y = f2bf(v.y); o.z = f2bf(v.z); o.w = f2bf(v.w);
      ((ushort4*)y)[i] = o;
    }
  } else if (bid < 2816) {
    const int t = bid - 2048;
    const int n0 = (t % 48) * 64;
    const int k0 = (t / 48) * 64;
    for (int i = threadIdx.x; i < 4096; i += 256) {
      int r = i >> 6, c = i & 63;
      sm[c * 65 + r] = f2bf(W[(size_t)(k0 + r) * 3072 + n0 + c]);
    }
    __syncthreads();
    for (int i = threadIdx.x; i < 4096; i += 256) {
      int r = i >> 6, c = i & 63;
      Wt[(size_t)(n0 + r) * 1024 + k0 + c] = sm[r * 65 + c];
    }
  } else {
#pragma unroll
    for (int k = 0; k < 8; k++)
      ((float4*)lsum)[k * 256 + threadIdx.x] = (float4)(0.f);
  }
}

// --------------------- merged qk + v GEMM dispatch -------------------------
// Both branches share the proven 128x128 mainloop and the SAME register
// class (VGPR ~112, 32KB LDS, 4 blk/CU).  R16: XCD-chunked bijective swizzle
// (1536 % 8 == 0): each XCD gets a contiguous 192-tile chunk so the 16
// N-blocks sharing one 256KB A-panel stay in ONE XCD's L2.
// swz < 1024: qk features -> qk[m 8192][n 2048] + bias, contiguous ushort4.
// swz >= 1024: v features -> vT[b][d][n] (swapped layout scatter).
__global__ __launch_bounds__(256) void k_gemm_qkv(
    const unsigned short* __restrict__ A, const unsigned short* __restrict__ Wt,
    const float* __restrict__ bias, unsigned short* __restrict__ qk,
    unsigned short* __restrict__ vT) {
  __shared__ unsigned short As[128 * 64];
  __shared__ unsigned short Bs[128 * 64];
  const int bid0 = blockIdx.x;
  const int bid = (bid0 & 7) * 192 + (bid0 >> 3);  // XCD chunk swizzle (T1)
  const int lane = threadIdx.x & 63, wave = threadIdx.x >> 6;
  if (bid < 1024) {
    // ---------------- qk branch ----------------
    f32x4 acc[4][4];
    const int tN0 = (bid & 15) * 128;
    const int tM0 = (bid >> 4) * 128;
    mma_mainloop(As, Bs, A + (size_t)tM0 * 1024, 1024,
                 Wt + (size_t)tN0 * 1024, 1024, 16, acc);
    const int ry = (wave >> 1) * 64, rx = (wave & 1) * 64;
    const int l16 = lane & 15, rq = lane >> 4;
#pragma unroll
    for (int mi = 0; mi < 4; mi++) {
      const int m = tM0 + ry + mi * 16 + l16;
#pragma unroll
      for (int nj = 0; nj < 4; nj++) {
        const int n = tN0 + rx + nj * 16 + rq * 4;
        const float4 bv = *(const float4*)&bias[n];
        ushort4 o;
        o.x = f2bf(acc[mi][nj][0] + bv.x);
        o.y = f2bf(acc[mi][nj][1] + bv.y);
        o.z = f2bf(acc[mi][nj][2] + bv.z);
        o.w = f2bf(acc[mi][nj][3] + bv.w);
        *(ushort4*)&qk[(size_t)m * 2048 + n] = o;
      }
    }
  } else {
    // ---------------- v branch ----------------
    f32x4 acc[4][4];
    const int idx = bid - 1024;
    const int tN0 = (idx & 7) * 128;   // v feature block
    const int tM0 = (idx >> 3) * 128;  // seq block
    mma_mainloop(As, Bs, A + (size_t)tM0 * 1024, 1024,
                 Wt + (size_t)(2048 + tN0) * 1024, 1024, 16, acc);
    int tM0v = tM0;
    asm volatile("" : "+v"(tM0v));  // block LICM of epilogue addresses into loop
    const int ry = (wave >> 1) * 64, rx = (wave & 1) * 64;
    const int l16 = lane & 15, rq = lane >> 4;
#pragma unroll
    for (int mi = 0; mi < 4; mi++) {
      const int m = tM0v + ry + mi * 16 + l16;  // global seq
      const int b = m >> 11, ns = m & 2047;
#pragma unroll
      for (int nj = 0; nj < 4; nj++) {
        const int d0 = tN0 + rx + nj * 16 + rq * 4;
        const float4 bv = *(const float4*)&bias[2048 + d0];
#pragma unroll
        for (int r = 0; r < 4; r++)
          vT[((size_t)(b * 1024 + d0 + r)) * 2048 + ns] =
              f2bf(acc[mi][nj][r] + ((const float*)&bv)[r]);
      }
    }
  }
}

// ------------------------- scores kernel (128x128, R17) --------------------
// P_unnorm 128x128 tile + row-sum atomics on the PROVEN mainloop (32 MFMA
// per barrier-pair, 8 gld16, 32KB LDS -- the gemm's register class).
// Triangular grid: t in 0..135 -> (qb, kb<=qb), z = batch.  K=16 iters.
__global__ __launch_bounds__(256) void k_scores(const unsigned short* __restrict__ qk,
                                                unsigned short* __restrict__ P,
                                                float* __restrict__ l, float scale) {
  __shared__ unsigned short As[128 * 64];
  __shared__ unsigned short Bs[128 * 64];
  const int t = blockIdx.x, b = blockIdx.z;
  int qb = (int)((sqrtf(8.0f * (float)t + 1.0f) - 1.0f) * 0.5f);  // qb(qb+1)/2 <= t
  while ((qb * (qb + 1)) >> 1 > t) qb--;
  while (((qb + 1) * (qb + 2)) >> 1 <= t) qb++;
  const int kb = t - ((qb * (qb + 1)) >> 1);  // 128-wide k tile, 0..qb
  f32x4 acc[4][4];
  const unsigned short* Aq = qk + ((size_t)(b * 2048 + qb * 128)) * 2048;
  const unsigned short* Bk = qk + ((size_t)(b * 2048 + kb * 128)) * 2048 + 1024;
  mma_mainloop(As, Bs, Aq, 2048, Bk, 2048, 16, acc);
  const int lane = threadIdx.x & 63, wave = threadIdx.x >> 6;
  const int ry = (wave >> 1) * 64, rx = (wave & 1) * 64;
  const int l16 = lane & 15, rq = lane >> 4;
  unsigned short* Pb = P + ((size_t)(b * 2048 + qb * 128)) * 2048 + (size_t)kb * 128;
  float* lb = l + b * 2048 + qb * 128;
#pragma unroll
  for (int mi = 0; mi < 4; mi++) {
    const int m_local = ry + mi * 16 + l16;
    const int qi = qb * 128 + m_local;
    float rowpart = 0.f;
#pragma unroll
    for (int nj = 0; nj < 4; nj++) {
      const int n_base = rx + nj * 16 + rq * 4;
      ushort4 o;
      float p;
#pragma unroll
      for (int r = 0; r < 4; r++) {
        const int kj = kb * 128 + n_base + r;
        p = (kj <= qi) ? __expf(acc[mi][nj][r] * scale) : 0.f;
        rowpart += p;
        ((unsigned short*)&o)[r] = f2bf(p);
      }
      *(ushort4*)&Pb[(size_t)m_local * 2048 + n_base] = o;
    }
    rowpart += __shfl_xor(rowpart, 16, 64);
    rowpart += __shfl_xor(rowpart, 32, 64);
    if (rq == 0) atomicAdd(&lb[m_local], rowpart);
  }
}

// ------------------------- pv kernel (128x128, R17) ------------------------
// out[m][d] = (P[m][:] @ vT[d][:]) / l[m] on the proven mainloop.
// 1-D grid 512, LONGEST-FIRST: qb = 15 - (t>>5); r = t&31: db = r>>2, b = r&3.
// Causal k-range (qb+1)*2 chunks of 64.
__global__ __launch_bounds__(256) void k_pv(const unsigned short* __restrict__ P,
                                            const unsigned short* __restrict__ vT,
                                            const float* __restrict__ l,
                                            float* __restrict__ out) {
  __shared__ unsigned short As[128 * 64];
  __shared__ unsigned short Bs[128 * 64];
  const int t = blockIdx.x;
  const int qb = 15 - (t >> 5);
  const int r = t & 31;
  const int db = r >> 2;
  const int b = r & 3;
  f32x4 acc[4][4];
  const unsigned short* Ap = P + ((size_t)(b * 2048 + qb * 128)) * 2048;
  const unsigned short* Bv = vT + ((size_t)(b * 1024 + db * 128)) * 2048;
  mma_mainloop(As, Bs, Ap, 2048, Bv, 2048, (qb + 1) * 2, acc);
  const int lane = threadIdx.x & 63, wave = threadIdx.x >> 6;
  const int ry = (wave >> 1) * 64, rx = (wave & 1) * 64;
  const int l16 = lane & 15, rq = lane >> 4;
  const float* lb = l + b * 2048 + qb * 128;
  float* ob = out + ((size_t)(b * 2048 + qb * 128)) * 1024 + db * 128;
#pragma unroll
  for (int mi = 0; mi < 4; mi++) {
    const int m_local = ry + mi * 16 + l16;
    const float inv = 1.0f / lb[m_local];
#pragma unroll
    for (int nj = 0; nj < 4; nj++) {
      const int n_base = rx + nj * 16 + rq * 4;
      float4 o;
      o.x = acc[mi][nj][0] * inv;
      o.y = acc[mi][nj][1] * inv;
      o.z = acc[mi][nj][2] * inv;
      o.w = acc[mi][nj][3] * inv;
      *(float4*)&ob[(size_t)m_local * 1024 + n_base] = o;
    }
  }
}

// ---------------------------------------------------------------------------

extern "C" void kernel_launch(void* const* d_in, const int* in_sizes, int n_in,
                              void* d_out, int out_size, void* d_ws, size_t ws_size,
                              hipStream_t stream) {
  const float* ctx  = (const float*)d_in[0];  // [4,2048,1024]
  const float* W    = (const float*)d_in[1];  // [1024,3072]
  const float* bias = (const float*)d_in[2];  // [3072]
  float* out = (float*)d_out;

  char* ws = (char*)d_ws;
  unsigned short* Actx = (unsigned short*)(ws + 0);          // 16,777,216
  unsigned short* Wt   = (unsigned short*)(ws + 16777216);   //  6,291,456
  unsigned short* qk   = (unsigned short*)(ws + 23068672);   // 33,554,432
  unsigned short* vT   = (unsigned short*)(ws + 56623104);   // 16,777,216
  unsigned short* P    = (unsigned short*)(ws + 73400320);   // 33,554,432
  float*          lsum = (float*)(ws + 106954752);           //     32,768

  k_prep<<<2817, 256, 0, stream>>>(ctx, Actx, W, Wt, lsum);
  k_gemm_qkv<<<1536, 256, 0, stream>>>(Actx, Wt, bias, qk, vT);
  k_scores<<<dim3(136, 1, 4), 256, 0, stream>>>(qk, P, lsum, 0.022097086912079608f);
  k_pv<<<512, 256, 0, stream>>>(P, vT, lsum, out);
}

// Round 10
// 222.487 us; speedup vs baseline: 1.0992x; 1.0992x over previous
//
#include <hip/hip_runtime.h>
#include <cstdint>
#include <cstddef>

// ---------------------------------------------------------------------------
// Attention_84155589198714: qkv = ctx @ W + b; causal softmax(q k^T / sqrt(N)); @ v
// B=4, N=2048, D=1024. All GEMMs in bf16 MFMA (16x16x32), fp32 accumulate.
//
// R2: XOR bank swizzle (conflicts -> 0); gld16 mainloop = 700 TF at 6 blk/CU.
// R4/R14/R15: merges only within one VGPR class; boundary savings ~=
//   occupancy losses otherwise.
// R9-R12: 256-wide tiles + counted-vmcnt schedules: neutral/worse. ABANDONED.
// R16: XCD-chunked swizzle on gemm: FETCH 136->57MB, 77us, frozen at its
//   issue-stall structural floor.
// R17: 128x128 scores/pv REGRESSED (+10us): halving block count 1088->544
//   dropped resident blocks/CU from ~4 to ~2 -- below the ~3 needed to hide
//   the m97-structure's barrier drain (m114).  Tile question CLOSED: 128x64
//   at >=1024 blocks is optimal for scores/pv.
// R18 (this): revert scores/pv to proven R16 forms; add T1 XCD-chunk swizzle
//   to k_scores x-dim (272%8==0, chunk 34, uniform K=16 -> balanced).
//   Consecutive triangular t share a 512KB Q-panel -> pin to one XCD L2.
//   pv NOT swizzled (chunking would skew causal depth across XCDs).
// ---------------------------------------------------------------------------

typedef __attribute__((ext_vector_type(8))) __bf16 bf16x8;
typedef __attribute__((ext_vector_type(4))) float f32x4;

__device__ inline unsigned short f2bf(float f) {
  unsigned u = __float_as_uint(f);
  u = (u + 0x7FFFu + ((u >> 16) & 1u)) >> 16;  // RNE
  return (unsigned short)u;
}

__device__ inline void gld16(const void* g, void* l) {
  __builtin_amdgcn_global_load_lds(
      (const __attribute__((address_space(1))) unsigned int*)g,
      (__attribute__((address_space(3))) unsigned int*)l, 16, 0, 0);
}

// --------------------- 128x128 tile machinery (gemms) ----------------------
// LDS layout per tile: row r = 64 elems at r*64; 8-elem chunk c of row r at
// chunk position c ^ (r&7) (XOR bank swizzle). Swapped-operand MFMA:
// output lane&15 = m (A row), 4 acc regs = 4 consecutive n (B row).
__device__ inline void compute_tiles(const unsigned short* As, const unsigned short* Bs,
                                     int lane, int ry, int rx, f32x4 acc[4][4]) {
#pragma unroll
  for (int kk = 0; kk < 64; kk += 32) {
    const int cbase = (kk >> 3) + (lane >> 4);
    const int csw = ((cbase ^ (lane & 7)) << 3);
    bf16x8 a[4], b[4];
#pragma unroll
    for (int mi = 0; mi < 4; mi++)
      a[mi] = *(const bf16x8*)&As[(ry + mi * 16 + (lane & 15)) * 64 + csw];
#pragma unroll
    for (int nj = 0; nj < 4; nj++)
      b[nj] = *(const bf16x8*)&Bs[(rx + nj * 16 + (lane & 15)) * 64 + csw];
#pragma unroll
    for (int mi = 0; mi < 4; mi++)
#pragma unroll
      for (int nj = 0; nj < 4; nj++)
        acc[mi][nj] = __builtin_amdgcn_mfma_f32_16x16x32_bf16(b[nj], a[mi], acc[mi][nj], 0, 0, 0);
  }
}

__device__ inline void mma_mainloop(unsigned short* As, unsigned short* Bs,
                                    const unsigned short* Abase, long strideA,
                                    const unsigned short* Bbase, long strideB,
                                    int kIters, f32x4 acc[4][4]) {
  const int lane = threadIdx.x & 63, wave = threadIdx.x >> 6;
  const int ry = (wave >> 1) * 64, rx = (wave & 1) * 64;
  const int lrow = lane >> 3;
  const int lcol = ((lane & 7) ^ lrow) * 8;
#pragma unroll
  for (int mi = 0; mi < 4; mi++)
#pragma unroll
    for (int nj = 0; nj < 4; nj++) acc[mi][nj] = (f32x4)(0.f);
  for (int kt = 0; kt < kIters; kt++) {
    const int k0 = kt * 64;
    __syncthreads();
#pragma unroll
    for (int c = 0; c < 4; c++) {
      const int q = wave * 4 + c;
      const int row = q * 8 + lrow;
      gld16(Abase + (size_t)row * strideA + k0 + lcol, &As[q * 512]);
      gld16(Bbase + (size_t)row * strideB + k0 + lcol, &Bs[q * 512]);
    }
    __syncthreads();
    compute_tiles(As, Bs, lane, ry, rx, acc);
  }
}

// --------------------- 128x64 tile machinery (scores/pv) -------------------
// M=128 (A rows), N=64 (B rows). 4 waves in 2x2; wave-tile 64x32.
// acc[4][2]: mi over 4x16 rows, nj over 2x16 cols.
__device__ inline void compute_tiles64(const unsigned short* As, const unsigned short* Bs,
                                       int lane, int ry, int rx, f32x4 acc[4][2]) {
#pragma unroll
  for (int kk = 0; kk < 64; kk += 32) {
    const int cbase = (kk >> 3) + (lane >> 4);
    const int csw = ((cbase ^ (lane & 7)) << 3);
    bf16x8 a[4], b[2];
#pragma unroll
    for (int mi = 0; mi < 4; mi++)
      a[mi] = *(const bf16x8*)&As[(ry + mi * 16 + (lane & 15)) * 64 + csw];
#pragma unroll
    for (int nj = 0; nj < 2; nj++)
      b[nj] = *(const bf16x8*)&Bs[(rx + nj * 16 + (lane & 15)) * 64 + csw];
#pragma unroll
    for (int mi = 0; mi < 4; mi++)
#pragma unroll
      for (int nj = 0; nj < 2; nj++)
        acc[mi][nj] = __builtin_amdgcn_mfma_f32_16x16x32_bf16(b[nj], a[mi], acc[mi][nj], 0, 0, 0);
  }
}

__device__ inline void mma_mainloop64(unsigned short* As, unsigned short* Bs,
                                      const unsigned short* Abase, long strideA,
                                      const unsigned short* Bbase, long strideB,
                                      int kIters, f32x4 acc[4][2]) {
  const int lane = threadIdx.x & 63, wave = threadIdx.x >> 6;
  const int ry = (wave >> 1) * 64, rx = (wave & 1) * 32;
  const int lrow = lane >> 3;
  const int lcol = ((lane & 7) ^ lrow) * 8;
#pragma unroll
  for (int mi = 0; mi < 4; mi++)
#pragma unroll
    for (int nj = 0; nj < 2; nj++) acc[mi][nj] = (f32x4)(0.f);
  for (int kt = 0; kt < kIters; kt++) {
    const int k0 = kt * 64;
    __syncthreads();
#pragma unroll
    for (int c = 0; c < 4; c++) {  // A: 16 chunks of 8 rows -> 4 per wave
      const int q = wave * 4 + c;
      const int row = q * 8 + lrow;
      gld16(Abase + (size_t)row * strideA + k0 + lcol, &As[q * 512]);
    }
#pragma unroll
    for (int c = 0; c < 2; c++) {  // B: 8 chunks -> 2 per wave
      const int q = wave * 2 + c;
      const int row = q * 8 + lrow;
      gld16(Bbase + (size_t)row * strideB + k0 + lcol, &Bs[q * 512]);
    }
    __syncthreads();
    compute_tiles64(As, Bs, lane, ry, rx, acc);
  }
}

// ------------------------ prep kernel (merged) -----------------------------
// bid < 2048: bf16 convert of ctx, 4 float4/thread (2048*1024 float4 total).
// 2048 <= bid < 2816: W [1024][3072] -> Wt [3072][1024] bf16 (768 64x64 tiles).
// bid == 2816: zero lsum (8192 floats).
__global__ void k_prep(const float* __restrict__ x, unsigned short* __restrict__ y,
                       const float* __restrict__ W, unsigned short* __restrict__ Wt,
                       float* __restrict__ lsum) {
  __shared__ unsigned short sm[64 * 65];
  const int bid = blockIdx.x;
  if (bid < 2048) {
#pragma unroll
    for (int k = 0; k < 4; k++) {
      const int i = bid * 1024 + k * 256 + threadIdx.x;
      float4 v = ((const float4*)x)[i];
      ushort4 o;
      o.x = f2bf(v.x); o.y = f2bf(v.y); o.z = f2bf(v.z); o.w = f2bf(v.w);
      ((ushort4*)y)[i] = o;
    }
  } else if (bid < 2816) {
    const int t = bid - 2048;
    const int n0 = (t % 48) * 64;
    const int k0 = (t / 48) * 64;
    for (int i = threadIdx.x; i < 4096; i += 256) {
      int r = i >> 6, c = i & 63;
      sm[c * 65 + r] = f2bf(W[(size_t)(k0 + r) * 3072 + n0 + c]);
    }
    __syncthreads();
    for (int i = threadIdx.x; i < 4096; i += 256) {
      int r = i >> 6, c = i & 63;
      Wt[(size_t)(n0 + r) * 1024 + k0 + c] = sm[r * 65 + c];
    }
  } else {
#pragma unroll
    for (int k = 0; k < 8; k++)
      ((float4*)lsum)[k * 256 + threadIdx.x] = (float4)(0.f);
  }
}

// --------------------- merged qk + v GEMM dispatch -------------------------
// Both branches share the proven 128x128 mainloop and the SAME register
// class (VGPR ~112, 32KB LDS, 4 blk/CU).  R16: XCD-chunked bijective swizzle
// (1536 % 8 == 0): each XCD gets a contiguous 192-tile chunk so the 16
// N-blocks sharing one 256KB A-panel stay in ONE XCD's L2.
// swz < 1024: qk features -> qk[m 8192][n 2048] + bias, contiguous ushort4.
// swz >= 1024: v features -> vT[b][d][n] (swapped layout scatter).
__global__ __launch_bounds__(256) void k_gemm_qkv(
    const unsigned short* __restrict__ A, const unsigned short* __restrict__ Wt,
    const float* __restrict__ bias, unsigned short* __restrict__ qk,
    unsigned short* __restrict__ vT) {
  __shared__ unsigned short As[128 * 64];
  __shared__ unsigned short Bs[128 * 64];
  const int bid0 = blockIdx.x;
  const int bid = (bid0 & 7) * 192 + (bid0 >> 3);  // XCD chunk swizzle (T1)
  const int lane = threadIdx.x & 63, wave = threadIdx.x >> 6;
  if (bid < 1024) {
    // ---------------- qk branch ----------------
    f32x4 acc[4][4];
    const int tN0 = (bid & 15) * 128;
    const int tM0 = (bid >> 4) * 128;
    mma_mainloop(As, Bs, A + (size_t)tM0 * 1024, 1024,
                 Wt + (size_t)tN0 * 1024, 1024, 16, acc);
    const int ry = (wave >> 1) * 64, rx = (wave & 1) * 64;
    const int l16 = lane & 15, rq = lane >> 4;
#pragma unroll
    for (int mi = 0; mi < 4; mi++) {
      const int m = tM0 + ry + mi * 16 + l16;
#pragma unroll
      for (int nj = 0; nj < 4; nj++) {
        const int n = tN0 + rx + nj * 16 + rq * 4;
        const float4 bv = *(const float4*)&bias[n];
        ushort4 o;
        o.x = f2bf(acc[mi][nj][0] + bv.x);
        o.y = f2bf(acc[mi][nj][1] + bv.y);
        o.z = f2bf(acc[mi][nj][2] + bv.z);
        o.w = f2bf(acc[mi][nj][3] + bv.w);
        *(ushort4*)&qk[(size_t)m * 2048 + n] = o;
      }
    }
  } else {
    // ---------------- v branch ----------------
    f32x4 acc[4][4];
    const int idx = bid - 1024;
    const int tN0 = (idx & 7) * 128;   // v feature block
    const int tM0 = (idx >> 3) * 128;  // seq block
    mma_mainloop(As, Bs, A + (size_t)tM0 * 1024, 1024,
                 Wt + (size_t)(2048 + tN0) * 1024, 1024, 16, acc);
    int tM0v = tM0;
    asm volatile("" : "+v"(tM0v));  // block LICM of epilogue addresses into loop
    const int ry = (wave >> 1) * 64, rx = (wave & 1) * 64;
    const int l16 = lane & 15, rq = lane >> 4;
#pragma unroll
    for (int mi = 0; mi < 4; mi++) {
      const int m = tM0v + ry + mi * 16 + l16;  // global seq
      const int b = m >> 11, ns = m & 2047;
#pragma unroll
      for (int nj = 0; nj < 4; nj++) {
        const int d0 = tN0 + rx + nj * 16 + rq * 4;
        const float4 bv = *(const float4*)&bias[2048 + d0];
#pragma unroll
        for (int r = 0; r < 4; r++)
          vT[((size_t)(b * 1024 + d0 + r)) * 2048 + ns] =
              f2bf(acc[mi][nj][r] + ((const float*)&bv)[r]);
      }
    }
  }
}

// ------------------------- scores kernel (proven + T1) ---------------------
// P_unnorm 128x64 tile + row-sum atomics. Triangular 1-D over (qb 16,
// kb2 2qb+2), z = batch, 272 tiles/batch.  R18: XCD-chunk swizzle on x
// (272 = 8 x 34, bijective; uniform K=16 -> balanced): consecutive t share
// the 512KB Q-panel -> one XCD's L2.
__global__ __launch_bounds__(256) void k_scores(const unsigned short* __restrict__ qk,
                                                unsigned short* __restrict__ P,
                                                float* __restrict__ l, float scale) {
  __shared__ unsigned short As[128 * 64];
  __shared__ unsigned short Bs[64 * 64];
  const int t0 = blockIdx.x, b = blockIdx.z;
  const int t = (t0 & 7) * 34 + (t0 >> 3);  // XCD chunk swizzle (T1)
  int qb = (int)((sqrtf(4.0f * (float)t + 1.0f) - 1.0f) * 0.5f);  // qb^2+qb <= t
  while (qb * (qb + 1) > t) qb--;
  while ((qb + 1) * (qb + 2) <= t) qb++;
  const int kb2 = t - qb * (qb + 1);  // 64-wide k tile, 0..2qb+1
  f32x4 acc[4][2];
  const unsigned short* Aq = qk + ((size_t)(b * 2048 + qb * 128)) * 2048;
  const unsigned short* Bk = qk + ((size_t)(b * 2048 + kb2 * 64)) * 2048 + 1024;
  mma_mainloop64(As, Bs, Aq, 2048, Bk, 2048, 16, acc);
  const int lane = threadIdx.x & 63, wave = threadIdx.x >> 6;
  const int ry = (wave >> 1) * 64, rx = (wave & 1) * 32;
  const int l16 = lane & 15, rq = lane >> 4;
  unsigned short* Pb = P + ((size_t)(b * 2048 + qb * 128)) * 2048 + (size_t)kb2 * 64;
  float* lb = l + b * 2048 + qb * 128;
#pragma unroll
  for (int mi = 0; mi < 4; mi++) {
    const int m_local = ry + mi * 16 + l16;
    const int qi = qb * 128 + m_local;
    float rowpart = 0.f;
#pragma unroll
    for (int nj = 0; nj < 2; nj++) {
      const int n_base = rx + nj * 16 + rq * 4;
      ushort4 o;
      float p;
#pragma unroll
      for (int r = 0; r < 4; r++) {
        const int kj = kb2 * 64 + n_base + r;
        p = (kj <= qi) ? __expf(acc[mi][nj][r] * scale) : 0.f;
        rowpart += p;
        ((unsigned short*)&o)[r] = f2bf(p);
      }
      *(ushort4*)&Pb[(size_t)m_local * 2048 + n_base] = o;
    }
    rowpart += __shfl_xor(rowpart, 16, 64);
    rowpart += __shfl_xor(rowpart, 32, 64);
    if (rq == 0) atomicAdd(&lb[m_local], rowpart);
  }
}

// ------------------------------- pv kernel ---------------------------------
// out[m][d] = (P[m][:] @ vT[d][:]) / l[m].  128x64 tiles, 1-D grid 1024,
// LONGEST-FIRST: t -> qb = 15 - (t>>6) (deep 32-step blocks dispatch first),
// db2 = (t&63)>>2, b = t&3.  Causal k-range (qb+1)*2 chunks.
__global__ __launch_bounds__(256) void k_pv(const unsigned short* __restrict__ P,
                                            const unsigned short* __restrict__ vT,
                                            const float* __restrict__ l,
                                            float* __restrict__ out) {
  __shared__ unsigned short As[128 * 64];
  __shared__ unsigned short Bs[64 * 64];
  const int t = blockIdx.x;
  const int qb = 15 - (t >> 6);
  const int r = t & 63;
  const int db2 = r >> 2;
  const int b = r & 3;
  f32x4 acc[4][2];
  const unsigned short* Ap = P + ((size_t)(b * 2048 + qb * 128)) * 2048;
  const unsigned short* Bv = vT + ((size_t)(b * 1024 + db2 * 64)) * 2048;
  mma_mainloop64(As, Bs, Ap, 2048, Bv, 2048, (qb + 1) * 2, acc);
  const int lane = threadIdx.x & 63, wave = threadIdx.x >> 6;
  const int ry = (wave >> 1) * 64, rx = (wave & 1) * 32;
  const int l16 = lane & 15, rq = lane >> 4;
  const float* lb = l + b * 2048 + qb * 128;
  float* ob = out + ((size_t)(b * 2048 + qb * 128)) * 1024 + db2 * 64;
#pragma unroll
  for (int mi = 0; mi < 4; mi++) {
    const int m_local = ry + mi * 16 + l16;
    const float inv = 1.0f / lb[m_local];
#pragma unroll
    for (int nj = 0; nj < 2; nj++) {
      const int n_base = rx + nj * 16 + rq * 4;
      float4 o;
      o.x = acc[mi][nj][0] * inv;
      o.y = acc[mi][nj][1] * inv;
      o.z = acc[mi][nj][2] * inv;
      o.w = acc[mi][nj][3] * inv;
      *(float4*)&ob[(size_t)m_local * 1024 + n_base] = o;
    }
  }
}

// ---------------------------------------------------------------------------

extern "C" void kernel_launch(void* const* d_in, const int* in_sizes, int n_in,
                              void* d_out, int out_size, void* d_ws, size_t ws_size,
                              hipStream_t stream) {
  const float* ctx  = (const float*)d_in[0];  // [4,2048,1024]
  const float* W    = (const float*)d_in[1];  // [1024,3072]
  const float* bias = (const float*)d_in[2];  // [3072]
  float* out = (float*)d_out;

  char* ws = (char*)d_ws;
  unsigned short* Actx = (unsigned short*)(ws + 0);          // 16,777,216
  unsigned short* Wt   = (unsigned short*)(ws + 16777216);   //  6,291,456
  unsigned short* qk   = (unsigned short*)(ws + 23068672);   // 33,554,432
  unsigned short* vT   = (unsigned short*)(ws + 56623104);   // 16,777,216
  unsigned short* P    = (unsigned short*)(ws + 73400320);   // 33,554,432
  float*          lsum = (float*)(ws + 106954752);           //     32,768

  k_prep<<<2817, 256, 0, stream>>>(ctx, Actx, W, Wt, lsum);
  k_gemm_qkv<<<1536, 256, 0, stream>>>(Actx, Wt, bias, qk, vT);
  k_scores<<<dim3(272, 1, 4), 256, 0, stream>>>(qk, P, lsum, 0.022097086912079608f);
  k_pv<<<1024, 256, 0, stream>>>(P, vT, lsum, out);
}